// Round 13
// baseline (207.855 us; speedup 1.0000x reference)
//
#include <hip/hip_runtime.h>
#include <cfloat>
#include <cstdint>

#define AN 100000   // anchors
#define GN 512      // ground truths
#define NC 80       // classes
#define KK 13       // topk

#define CHUNKS 16
#define CH_LEN 6400               // 15 full chunks of 25 tiles; last = 4000 (15 tiles + 160)
#define DUMP 16                   // dump slots per (g, chunk): 13 + pad
#define GSLICE 8
#define GPS (GN / GSLICE)         // 64

typedef unsigned long long ull;

// fast reciprocal: v_rcp_f32 (<=1 ulp); outputs bf16-compared (threshold 1.6)
__device__ __forceinline__ float rcpf(float x)
{
    float r; asm("v_rcp_f32 %0, %1" : "=v"(r) : "v"(x)); return r;
}

// 6th-root with downward margin: filter constant. Margin 1e-4 >> ulp error of
// rcp/log/exp chains, so  metric > th  ==>  inter > c*(uni+eps)  is guaranteed.
__device__ __forceinline__ float root6_down(float th)
{
    return exp2f(log2f(th) * (1.0f / 6.0f)) * 0.9999f;   // th=0 -> 0
}

// iou^6 (no score) — used in prime/argmax/fallback paths
__device__ __forceinline__ float iou6r(float4 g, float ga, float4 p)
{
    float pa = (p.z - p.x) * (p.w - p.y);
    float ltx = fmaxf(g.x, p.x), lty = fmaxf(g.y, p.y);
    float rbx = fminf(g.z, p.z), rby = fminf(g.w, p.w);
    float w = fmaxf(rbx - ltx, 0.0f), h = fmaxf(rby - lty, 0.0f);
    float inter = w * h;
    float uni = ga + pa - inter;
    float iou = inter * rcpf(uni + 1e-9f);
    float i2 = iou * iou;
    return i2 * i2 * i2;
}

// order-preserving float->uint map (total order; works for -FLT_MAX sentinel)
__device__ __forceinline__ unsigned f2ord(float f)
{
    unsigned b = __float_as_uint(f);
    return b ^ (unsigned)(((int)b >> 31) | 0x80000000);
}
__device__ __forceinline__ float ord2f(unsigned u)
{
    unsigned b = (u & 0x80000000u) ? (u ^ 0x80000000u) : ~u;
    return __uint_as_float(b);
}

// compare-swap: keep better (value desc, index asc) in (va, ia)
__device__ __forceinline__ void csw(float& va, int& ia, float& vb, int& ib)
{
    bool sw = (va < vb) || (va == vb && ia > ib);
    float tv = sw ? vb : va; int ti = sw ? ib : ia;
    vb = sw ? va : vb; ib = sw ? ia : ib;
    va = tv; ia = ti;
}

// wave-synchronous LDS fence
__device__ __forceinline__ void wsync()
{
    __builtin_amdgcn_sched_barrier(0);
    asm volatile("s_waitcnt lgkmcnt(0)" ::: "memory");
    __builtin_amdgcn_sched_barrier(0);
}

// Exact top-13 of {incumbents (lane r<13 holds rank r) ∪ cand[0..n)} where
// cand_v holds METRICS (LDS + registers only). n <= 511.
__device__ float flush_m(int lane, int n, const float* cand_v, const int* cand_i,
                         float& inc_v, int& inc_i)
{
    wsync();                               // appended cand visible wave-wide
    float v[8]; int ix[8];
    #pragma unroll
    for (int k = 0; k < 8; ++k) {
        int j = lane + (k << 6);
        bool ok = j < n;
        v[k]  = ok ? cand_v[j] : -FLT_MAX;
        ix[k] = ok ? cand_i[j] : 0x7fffffff;
    }
    csw(v[0],ix[0],v[1],ix[1]); csw(v[2],ix[2],v[3],ix[3]);
    csw(v[4],ix[4],v[5],ix[5]); csw(v[6],ix[6],v[7],ix[7]);
    csw(v[0],ix[0],v[2],ix[2]); csw(v[1],ix[1],v[3],ix[3]);
    csw(v[4],ix[4],v[6],ix[6]); csw(v[5],ix[5],v[7],ix[7]);
    csw(v[1],ix[1],v[2],ix[2]); csw(v[5],ix[5],v[6],ix[6]);
    csw(v[0],ix[0],v[4],ix[4]); csw(v[1],ix[1],v[5],ix[5]);
    csw(v[2],ix[2],v[6],ix[6]); csw(v[3],ix[3],v[7],ix[7]);
    csw(v[2],ix[2],v[4],ix[4]); csw(v[3],ix[3],v[5],ix[5]);
    csw(v[1],ix[1],v[2],ix[2]); csw(v[3],ix[3],v[4],ix[4]);
    csw(v[5],ix[5],v[6],ix[6]);
    bool c[8];
    #pragma unroll
    for (int j = 0; j < 8; ++j)
        c[j] = (v[j] > inc_v) || (v[j] == inc_v && ix[j] < inc_i);
    float h[9]; int hi[9];
    h[0] = c[0] ? v[0] : inc_v;  hi[0] = c[0] ? ix[0] : inc_i;
    #pragma unroll
    for (int j = 1; j < 8; ++j) {
        h[j]  = c[j] ? v[j]  : (c[j-1] ? inc_v : v[j-1]);
        hi[j] = c[j] ? ix[j] : (c[j-1] ? inc_i : ix[j-1]);
    }
    h[8] = c[7] ? inc_v : v[7];  hi[8] = c[7] ? inc_i : ix[7];

    float th = -FLT_MAX;
    #pragma unroll
    for (int r = 0; r < KK; ++r) {
        ull myp = ((ull)f2ord(h[0]) << 32) | (unsigned)(~hi[0]);
        ull p = myp;
        #pragma unroll
        for (int o = 32; o >= 1; o >>= 1) {
            ull q = __shfl_xor(p, o);
            p = p > q ? p : q;
        }
        float wv = ord2f((unsigned)(p >> 32));
        int   wi = (int)~((unsigned)p);
        if (lane == r) { inc_v = wv; inc_i = wi; }
        bool pop = (myp == p);
        #pragma unroll
        for (int j = 0; j < 8; ++j) {
            h[j]  = pop ? h[j+1]  : h[j];
            hi[j] = pop ? hi[j+1] : hi[j];
        }
        h[8]  = pop ? -FLT_MAX   : h[8];
        hi[8] = pop ? 0x7fffffff : hi[8];
        th = wv;
    }
    return th;
}

// Insert into register-resident sorted-13 (fallback kernels only).
__device__ __forceinline__ void insert13(float* v, int* ix, float m, int a)
{
    bool worse = (m < v[KK - 1]) || (m == v[KK - 1] && a > ix[KK - 1]);
    if (worse) return;
    int p = 0;
    #pragma unroll
    for (int j = 0; j < KK; ++j)
        p += ((v[j] > m) || (v[j] == m && ix[j] < a)) ? 1 : 0;
    #pragma unroll
    for (int j = KK - 1; j >= 1; --j) {
        bool sh = (j > p);
        v[j]  = sh ? v[j - 1]  : v[j];
        ix[j] = sh ? ix[j - 1] : ix[j];
    }
    #pragma unroll
    for (int j = 0; j < KK; ++j) if (j == p) { v[j] = m; ix[j] = a; }
}

// ---------------- pd_scores [AN][NC] -> scT [NC][AN] ----------------
__global__ __launch_bounds__(256) void transpose_scores(
    const float* __restrict__ ps, float* __restrict__ scT)
{
    __shared__ float tile[64][NC + 1];
    int a0 = blockIdx.x * 64;
    int tid = threadIdx.x;
    for (int i = tid; i < 64 * NC / 4; i += 256) {
        int fi = i * 4;
        int a = fi / NC, c = fi % NC;
        if (a0 + a < AN) {
            float4 v = *reinterpret_cast<const float4*>(ps + (size_t)(a0 + a) * NC + c);
            tile[a][c] = v.x; tile[a][c + 1] = v.y; tile[a][c + 2] = v.z; tile[a][c + 3] = v.w;
        }
    }
    __syncthreads();
    int j = tid & 63, cg = tid >> 6;
    int a = a0 + j;
    if (a < AN) {
        for (int c = cg; c < NC; c += 4)
            scT[(size_t)c * AN + a] = tile[j][c];
    }
}

// ---------------- argmax pass A1 (predicated — no branches) ----------------
// Prefilter (predicated): scores <= 1.0 so m = sc*iou6 <= iou6; if
// iou6 <= best the strict-> update cannot fire — skip the scT gather.
__global__ __launch_bounds__(256) void argmax_part(
    const float* __restrict__ pd_bboxes,
    const int*   __restrict__ gt_labels,
    const float* __restrict__ gt_bboxes,
    const float* __restrict__ scT,
    ull* __restrict__ part)
{
    __shared__ float4 gb[GPS];
    __shared__ float  ga[GPS];
    __shared__ int    glb[GPS];
    int slice = blockIdx.x & (GSLICE - 1);
    int ab = (blockIdx.x >> 3) * 512;
    int tid = threadIdx.x;
    int g0 = slice * GPS;
    if (tid < GPS) {
        float4 bb = ((const float4*)gt_bboxes)[g0 + tid];
        gb[tid] = bb;
        ga[tid] = (bb.z - bb.x) * (bb.w - bb.y);
        glb[tid] = gt_labels[g0 + tid];
    }
    __syncthreads();
    int aa = ab + tid, ab2 = ab + 256 + tid;
    bool okA = aa < AN, okB = ab2 < AN;
    int ca = okA ? aa : AN - 1, cb = okB ? ab2 : AN - 1;
    float4 pba = ((const float4*)pd_bboxes)[ca];
    float4 pbb = ((const float4*)pd_bboxes)[cb];
    float bestA = -1.0f, bestB = -1.0f;
    int bgA = 0, bgB = 0;
    for (int i = 0; i < GPS; ++i) {
        float4 gx = gb[i];
        float gax = ga[i];
        int lab = glb[i];
        const float* srow = scT + (size_t)lab * AN;
        float i6a = iou6r(gx, gax, pba);
        float i6b = iou6r(gx, gax, pbb);
        float sa = (i6a > bestA) ? srow[ca] : 0.0f;   // predicated gather
        float sb = (i6b > bestB) ? srow[cb] : 0.0f;
        float ma = sa * i6a;
        float mb = sb * i6b;
        if (ma > bestA) { bestA = ma; bgA = i; }      // strict > => first-occurrence
        if (mb > bestB) { bestB = mb; bgB = i; }
    }
    if (okA)
        part[(size_t)slice * AN + aa] =
            ((ull)__float_as_uint(bestA) << 32) | (ull)(0xFFFFFFFFu - (unsigned)(g0 + bgA));
    if (okB)
        part[(size_t)slice * AN + ab2] =
            ((ull)__float_as_uint(bestB) << 32) | (ull)(0xFFFFFFFFu - (unsigned)(g0 + bgB));
}

// ---------------- argmax pass A2 ----------------
__global__ __launch_bounds__(256) void argmax_combine(
    const ull* __restrict__ part,
    const int* __restrict__ gt_labels,
    const float* __restrict__ gt_bboxes,
    float* __restrict__ out)
{
    int a = blockIdx.x * 256 + threadIdx.x;
    if (a >= AN) return;
    ull p = part[a];
    #pragma unroll
    for (int s = 1; s < GSLICE; ++s) {
        ull q = part[(size_t)s * AN + a];
        p = p > q ? p : q;
    }
    unsigned g = 0xFFFFFFFFu - (unsigned)(p & 0xFFFFFFFFull);
    float best = __uint_as_float((unsigned)(p >> 32));
    out[a] = (best <= 0.0f) ? (float)NC : (float)gt_labels[g];
    ((float4*)(out + AN))[a] = ((const float4*)gt_bboxes)[g];
    out[(size_t)5 * AN + a] = best;
}

// ---------------- topk pass 1 ----------------
// 4 waves/block at lb(256,4) — VGPR cap 128, NO spilling (the lb(,8) 32-VGPR
// cap caused ~500MB scratch traffic in rounds 9/11 — never use it here).
// CHUNKS 16 -> 2048 blocks -> 8 blocks/CU -> 32 waves/CU. Tile-0 prime sets
// exact th; steady state: division-free inter > cth*(uni+eps) filter, gather
// scores only for hits, exact re-test, append metrics. Flushes LDS-only.
template<bool FULL>
__device__ __forceinline__ void loadB(int tb, int lane,
    const float4* __restrict__ pd4,
    float4& B0, float4& B1, float4& B2, float4& B3)
{
    int a0 = tb + lane;
    if (FULL) {
        B0 = pd4[a0]; B1 = pd4[a0 + 64]; B2 = pd4[a0 + 128]; B3 = pd4[a0 + 192];
    } else {
        B0 = pd4[min(a0,       AN - 1)];
        B1 = pd4[min(a0 + 64,  AN - 1)];
        B2 = pd4[min(a0 + 128, AN - 1)];
        B3 = pd4[min(a0 + 192, AN - 1)];
    }
}

template<bool FULL>
__device__ __forceinline__ void procB(
    int tb, int aend, int lane, uint64_t lt,
    float4 B0, float4 B1, float4 B2, float4 B3,
    const float* __restrict__ srow,
    float4 b, float gax, float& th, float& cth, int& cnt,
    float* cand_v, int* cand_i, float& inc_v, int& inc_i)
{
    int a0 = tb + lane, a1 = a0 + 64, a2 = a0 + 128, a3 = a0 + 192;
    // intersection/union only — no division in the hot path
    float lx0 = fmaxf(b.x, B0.x), ly0 = fmaxf(b.y, B0.y);
    float rx0 = fminf(b.z, B0.z), ry0 = fminf(b.w, B0.w);
    float w0 = fmaxf(rx0 - lx0, 0.0f), h0f = fmaxf(ry0 - ly0, 0.0f);
    float in0 = w0 * h0f;
    float ue0 = gax + (B0.z - B0.x) * (B0.w - B0.y) - in0 + 1e-9f;
    float lx1 = fmaxf(b.x, B1.x), ly1 = fmaxf(b.y, B1.y);
    float rx1 = fminf(b.z, B1.z), ry1 = fminf(b.w, B1.w);
    float w1 = fmaxf(rx1 - lx1, 0.0f), h1f = fmaxf(ry1 - ly1, 0.0f);
    float in1 = w1 * h1f;
    float ue1 = gax + (B1.z - B1.x) * (B1.w - B1.y) - in1 + 1e-9f;
    float lx2 = fmaxf(b.x, B2.x), ly2 = fmaxf(b.y, B2.y);
    float rx2 = fminf(b.z, B2.z), ry2 = fminf(b.w, B2.w);
    float w2 = fmaxf(rx2 - lx2, 0.0f), h2f = fmaxf(ry2 - ly2, 0.0f);
    float in2 = w2 * h2f;
    float ue2 = gax + (B2.z - B2.x) * (B2.w - B2.y) - in2 + 1e-9f;
    float lx3 = fmaxf(b.x, B3.x), ly3 = fmaxf(b.y, B3.y);
    float rx3 = fminf(b.z, B3.z), ry3 = fminf(b.w, B3.w);
    float w3 = fmaxf(rx3 - lx3, 0.0f), h3f = fmaxf(ry3 - ly3, 0.0f);
    float in3 = w3 * h3f;
    float ue3 = gax + (B3.z - B3.x) * (B3.w - B3.y) - in3 + 1e-9f;
    // superset filter: m > th ==> iou6 > th ==> inter > cth*(uni+eps)
    bool h0 = (in0 > cth * ue0) && (FULL || a0 < aend);
    bool h1 = (in1 > cth * ue1) && (FULL || a1 < aend);
    bool h2 = (in2 > cth * ue2) && (FULL || a2 < aend);
    bool h3 = (in3 > cth * ue3) && (FULL || a3 < aend);
    if (__any(h0 | h1 | h2 | h3)) {
        int c0 = FULL ? a0 : min(a0, AN - 1);
        int c1 = FULL ? a1 : min(a1, AN - 1);
        int c2 = FULL ? a2 : min(a2, AN - 1);
        int c3 = FULL ? a3 : min(a3, AN - 1);
        // exact metric (bit-identical to iou6r path), gather hit lanes only
        float io0 = in0 * rcpf(ue0); float q0 = io0 * io0; float i60 = q0 * q0 * q0;
        float io1 = in1 * rcpf(ue1); float q1 = io1 * io1; float i61 = q1 * q1 * q1;
        float io2 = in2 * rcpf(ue2); float q2 = io2 * io2; float i62 = q2 * q2 * q2;
        float io3 = in3 * rcpf(ue3); float q3 = io3 * io3; float i63 = q3 * q3 * q3;
        float s0 = h0 ? srow[c0] : 0.0f;
        float s1 = h1 ? srow[c1] : 0.0f;
        float s2 = h2 ? srow[c2] : 0.0f;
        float s3 = h3 ? srow[c3] : 0.0f;
        float m0 = s0 * i60, m1 = s1 * i61, m2 = s2 * i62, m3 = s3 * i63;
        // exact re-test; m == th loses the index tie to incumbents anyway
        h0 = h0 && (m0 > th); h1 = h1 && (m1 > th);
        h2 = h2 && (m2 > th); h3 = h3 && (m3 > th);
        uint64_t B;
        B = __ballot(h0);
        if (h0) { int p = cnt + __popcll(B & lt); cand_v[p] = m0; cand_i[p] = a0; }
        cnt += __popcll(B);
        B = __ballot(h1);
        if (h1) { int p = cnt + __popcll(B & lt); cand_v[p] = m1; cand_i[p] = a1; }
        cnt += __popcll(B);
        B = __ballot(h2);
        if (h2) { int p = cnt + __popcll(B & lt); cand_v[p] = m2; cand_i[p] = a2; }
        cnt += __popcll(B);
        B = __ballot(h3);
        if (h3) { int p = cnt + __popcll(B & lt); cand_v[p] = m3; cand_i[p] = a3; }
        cnt += __popcll(B);
        if (cnt >= 256) {                 // cap: 255 + 256 = 511 < 512
            th = flush_m(lane, cnt, cand_v, cand_i, inc_v, inc_i);
            cth = root6_down(th);
            cnt = 0;
        }
    }
}

__global__ __launch_bounds__(256, 4) void topk_pass1(
    const float* __restrict__ pd_bboxes,
    const int*   __restrict__ gt_labels,
    const float* __restrict__ gt_bboxes,
    const float* __restrict__ scT,
    float* __restrict__ out_v, int* __restrict__ out_i)
{
    __shared__ float cvA[4][512];
    __shared__ int   ciA[4][512];
    int w = threadIdx.x >> 6, lane = threadIdx.x & 63;
    float* cand_v = cvA[w]; int* cand_i = ciA[w];
    uint64_t lt = (1ull << lane) - 1ull;
    int gid = blockIdx.x * 4 + w;
    int g = gid & (GN - 1), c = gid >> 9;

    float4 b = ((const float4*)gt_bboxes)[g];
    float gax = (b.z - b.x) * (b.w - b.y);
    int lab = gt_labels[g];
    const float* srow = scT + (size_t)lab * AN;
    const float4* pd4 = (const float4*)pd_bboxes;

    int base = c * CH_LEN;
    int len = min(CH_LEN, AN - base);
    int aend = base + len;
    int nfull = len >> 8;                 // 25 (chunks 0-14) or 15 (chunk 15)
    int rem = len & 255;                  // 0 or 160

    float inc_v = -FLT_MAX; int inc_i = 0x7fffffff;   // lane r<13: rank r (metric)
    int cnt = 0;

    // ---- tile 0 prime: dense scores, exact top-13 of first 256 anchors ----
    float4 X0, X1, X2, X3, Y0, Y1, Y2, Y3;
    {
        int a0 = base + lane;
        loadB<true>(base, lane, pd4, X0, X1, X2, X3);
        float s0 = srow[a0], s1 = srow[a0 + 64], s2 = srow[a0 + 128], s3 = srow[a0 + 192];
        cand_v[lane]       = s0 * iou6r(b, gax, X0);  cand_i[lane]       = a0;
        cand_v[lane + 64]  = s1 * iou6r(b, gax, X1);  cand_i[lane + 64]  = a0 + 64;
        cand_v[lane + 128] = s2 * iou6r(b, gax, X2);  cand_i[lane + 128] = a0 + 128;
        cand_v[lane + 192] = s3 * iou6r(b, gax, X3);  cand_i[lane + 192] = a0 + 192;
    }
    float th = flush_m(lane, 256, cand_v, cand_i, inc_v, inc_i);
    float cth = root6_down(th);

    // ---- tiles 1..nfull-1, double-buffered bbox pipeline ----
    int i = 1, tb = base + 256;
    if (nfull > 1) {
        loadB<true>(tb, lane, pd4, X0, X1, X2, X3);
        while (true) {
            if (i + 1 < nfull) loadB<true>(tb + 256, lane, pd4, Y0, Y1, Y2, Y3);
            procB<true>(tb, aend, lane, lt, X0, X1, X2, X3, srow,
                        b, gax, th, cth, cnt, cand_v, cand_i, inc_v, inc_i);
            ++i; tb += 256;
            if (i >= nfull) break;
            if (i + 1 < nfull) loadB<true>(tb + 256, lane, pd4, X0, X1, X2, X3);
            procB<true>(tb, aend, lane, lt, Y0, Y1, Y2, Y3, srow,
                        b, gax, th, cth, cnt, cand_v, cand_i, inc_v, inc_i);
            ++i; tb += 256;
            if (i >= nfull) break;
        }
    }
    if (rem) {                            // tail tile (last chunk only)
        loadB<false>(tb, lane, pd4, X0, X1, X2, X3);
        procB<false>(tb, aend, lane, lt, X0, X1, X2, X3, srow,
                     b, gax, th, cth, cnt, cand_v, cand_i, inc_v, inc_i);
    }

    if (cnt > 0)
        flush_m(lane, cnt, cand_v, cand_i, inc_v, inc_i);

    if (lane < DUMP) {
        size_t o = ((size_t)g * CHUNKS + c) * DUMP + lane;
        out_v[o] = (lane < KK) ? inc_v : -FLT_MAX;
        out_i[o] = (lane < KK) ? inc_i : 0x7fffffff;
    }
}

// ---------------- topk pass 2: zero row + merge 16x16 dumps + scatter ----------------
__global__ __launch_bounds__(256) void topk_finalize(
    const float* __restrict__ in_v, const int* __restrict__ in_i,
    float* __restrict__ mask)
{
    int g = blockIdx.x, tid = threadIdx.x;
    float4* row4 = (float4*)(mask + (size_t)g * AN);
    float4 z = make_float4(0.f, 0.f, 0.f, 0.f);
    for (int j = tid; j < AN / 4; j += 256) row4[j] = z;
    __syncthreads();
    if (tid >= 64) return;
    int lane = tid;
    size_t rb = (size_t)g * (CHUNKS * DUMP);     // 256 entries
    float v0 = in_v[rb + lane],       v1 = in_v[rb + 64 + lane];
    float v2 = in_v[rb + 128 + lane], v3 = in_v[rb + 192 + lane];
    int   i0 = in_i[rb + lane],       i1 = in_i[rb + 64 + lane];
    int   i2 = in_i[rb + 128 + lane], i3 = in_i[rb + 192 + lane];
    csw(v0, i0, v1, i1); csw(v2, i2, v3, i3);
    csw(v0, i0, v2, i2); csw(v1, i1, v3, i3);
    csw(v1, i1, v2, i2);                          // sorted desc v0..v3
    #pragma unroll
    for (int r = 0; r < KK; ++r) {
        ull myp = ((ull)f2ord(v0) << 32) | (unsigned)(~i0);
        ull p = myp;
        #pragma unroll
        for (int o = 32; o >= 1; o >>= 1) {
            ull q = __shfl_xor(p, o);
            p = p > q ? p : q;
        }
        int wi = (int)~((unsigned)p);
        if (lane == r) mask[(size_t)g * AN + wi] = 1.0f;
        bool pop = (myp == p);
        v0 = pop ? v1 : v0;  i0 = pop ? i1 : i0;
        v1 = pop ? v2 : v1;  i1 = pop ? i2 : i1;
        v2 = pop ? v3 : v2;  i2 = pop ? i3 : i2;
        v3 = pop ? -FLT_MAX : v3;  i3 = pop ? 0x7fffffff : i3;
    }
}

// ---------------- fallbacks (small workspace) ----------------
__global__ __launch_bounds__(256) void argmax_kernel(
    const float* __restrict__ pd_scores,
    const float* __restrict__ pd_bboxes,
    const int*   __restrict__ gt_labels,
    const float* __restrict__ gt_bboxes,
    const float* __restrict__ scT, int use_t,
    float* __restrict__ out)
{
    __shared__ float4 gb[GN];
    __shared__ float  ga[GN];
    __shared__ int    gl[GN];
    int tid = threadIdx.x;
    for (int g = tid; g < GN; g += 256) {
        float4 b = reinterpret_cast<const float4*>(gt_bboxes)[g];
        gb[g] = b;
        ga[g] = (b.z - b.x) * (b.w - b.y);
        gl[g] = gt_labels[g];
    }
    __syncthreads();
    int a = blockIdx.x * 256 + tid;
    if (a >= AN) return;
    float4 pb = reinterpret_cast<const float4*>(pd_bboxes)[a];
    float best = -1.0f; int bg = 0;
    for (int g = 0; g < GN; ++g) {
        int lab = gl[g];
        float sc = use_t ? scT[(size_t)lab * AN + a] : pd_scores[(size_t)a * NC + lab];
        float m = sc * iou6r(gb[g], ga[g], pb);
        if (m > best) { best = m; bg = g; }
    }
    out[a] = (best <= 0.0f) ? (float)NC : (float)gl[bg];
    reinterpret_cast<float4*>(out + AN)[a] = gb[bg];
    out[5 * AN + a] = best;
}

__global__ __launch_bounds__(256) void topk_kernel_fallback(
    const float* __restrict__ pd_scores,
    const float* __restrict__ pd_bboxes,
    const int*   __restrict__ gt_labels,
    const float* __restrict__ gt_bboxes,
    const float* __restrict__ scT, int use_t,
    float* __restrict__ mask)
{
    __shared__ float sv[256 * KK];
    __shared__ int   si[256 * KK];
    int g = blockIdx.x, tid = threadIdx.x;
    float4 b = reinterpret_cast<const float4*>(gt_bboxes)[g];
    float gax = (b.z - b.x) * (b.w - b.y);
    int lab = gt_labels[g];
    float v[KK]; int idx[KK];
    #pragma unroll
    for (int j = 0; j < KK; ++j) { v[j] = -FLT_MAX; idx[j] = 0x7fffffff; }
    for (int a = tid; a < AN; a += 256) {
        float4 pb = reinterpret_cast<const float4*>(pd_bboxes)[a];
        float sc = use_t ? scT[(size_t)lab * AN + a] : pd_scores[(size_t)a * NC + lab];
        float m = sc * iou6r(b, gax, pb);
        insert13(v, idx, m, a);
    }
    #pragma unroll
    for (int j = 0; j < KK; ++j) { sv[tid * KK + j] = v[j]; si[tid * KK + j] = idx[j]; }
    for (int off = 128; off >= 1; off >>= 1) {
        __syncthreads();
        if (tid < off) {
            int i = 0, jj = 0;
            float ov[KK]; int oi[KK];
            #pragma unroll
            for (int t = 0; t < KK; ++t) {
                float va = sv[tid * KK + i];          int ia = si[tid * KK + i];
                float vb = sv[(tid + off) * KK + jj]; int ib = si[(tid + off) * KK + jj];
                bool ta = (va > vb) || (va == vb && ia < ib);
                ov[t] = ta ? va : vb; oi[t] = ta ? ia : ib;
                i += ta ? 1 : 0; jj += ta ? 0 : 1;
            }
            #pragma unroll
            for (int t = 0; t < KK; ++t) { sv[tid * KK + t] = ov[t]; si[tid * KK + t] = oi[t]; }
        }
    }
    __syncthreads();
    if (tid < KK) mask[(size_t)g * AN + si[tid]] = 1.0f;
}

extern "C" void kernel_launch(void* const* d_in, const int* in_sizes, int n_in,
                              void* d_out, int out_size, void* d_ws, size_t ws_size,
                              hipStream_t stream)
{
    const float* pd_scores = (const float*)d_in[0];
    const float* pd_bboxes = (const float*)d_in[1];
    const int*   gt_labels = (const int*)d_in[2];
    const float* gt_bboxes = (const float*)d_in[3];
    float* out  = (float*)d_out;
    float* mask = out + (size_t)6 * AN;

    const size_t scT_b  = (size_t)NC * AN * sizeof(float);           // 32.0 MB
    const size_t auxn   = (size_t)GN * CHUNKS * DUMP;                // 131072
    const size_t aux_b  = auxn * 8;                                  // 1.05 MB
    const size_t part_b = (size_t)GSLICE * AN * sizeof(ull);         // 6.4 MB

    float* scT   = (float*)d_ws;
    float* aux_v = (float*)((char*)d_ws + scT_b);
    int*   aux_i = (int*)(aux_v + auxn);
    ull*   part  = (ull*)((char*)d_ws + scT_b + aux_b);

    if (ws_size >= scT_b + aux_b + part_b) {
        transpose_scores<<<(AN + 63) / 64, 256, 0, stream>>>(pd_scores, scT);
        topk_pass1<<<GN * CHUNKS / 4, 256, 0, stream>>>(
            pd_bboxes, gt_labels, gt_bboxes, scT, aux_v, aux_i);
        topk_finalize<<<GN, 256, 0, stream>>>(aux_v, aux_i, mask);
        argmax_part<<<((AN + 511) / 512) * GSLICE, 256, 0, stream>>>(
            pd_bboxes, gt_labels, gt_bboxes, scT, part);
        argmax_combine<<<(AN + 255) / 256, 256, 0, stream>>>(
            part, gt_labels, gt_bboxes, out);
    } else if (ws_size >= scT_b + aux_b) {
        transpose_scores<<<(AN + 63) / 64, 256, 0, stream>>>(pd_scores, scT);
        topk_pass1<<<GN * CHUNKS / 4, 256, 0, stream>>>(
            pd_bboxes, gt_labels, gt_bboxes, scT, aux_v, aux_i);
        topk_finalize<<<GN, 256, 0, stream>>>(aux_v, aux_i, mask);
        argmax_kernel<<<(AN + 255) / 256, 256, 0, stream>>>(
            pd_scores, pd_bboxes, gt_labels, gt_bboxes, scT, 1, out);
    } else if (ws_size >= scT_b) {
        hipMemsetAsync(mask, 0, (size_t)GN * AN * sizeof(float), stream);
        transpose_scores<<<(AN + 63) / 64, 256, 0, stream>>>(pd_scores, scT);
        argmax_kernel<<<(AN + 255) / 256, 256, 0, stream>>>(
            pd_scores, pd_bboxes, gt_labels, gt_bboxes, scT, 1, out);
        topk_kernel_fallback<<<GN, 256, 0, stream>>>(
            pd_scores, pd_bboxes, gt_labels, gt_bboxes, scT, 1, mask);
    } else {
        hipMemsetAsync(mask, 0, (size_t)GN * AN * sizeof(float), stream);
        argmax_kernel<<<(AN + 255) / 256, 256, 0, stream>>>(
            pd_scores, pd_bboxes, gt_labels, gt_bboxes, scT, 0, out);
        topk_kernel_fallback<<<GN, 256, 0, stream>>>(
            pd_scores, pd_bboxes, gt_labels, gt_bboxes, scT, 0, mask);
    }
}

// Round 14
// 181.439 us; speedup vs baseline: 1.1456x; 1.1456x over previous
//
#include <hip/hip_runtime.h>
#include <cfloat>
#include <cstdint>

#define AN 100000   // anchors
#define GN 512      // ground truths
#define NC 80       // classes
#define KK 13       // topk

#define CHUNKS 8
#define CH_LEN 12544              // 7*12544 = 87808; last chunk 12192
#define DUMP 16                   // dump slots per (g, chunk): 13 + pad
#define GSLICE 8
#define GPS (GN / GSLICE)         // 64

typedef unsigned long long ull;

// fast reciprocal: v_rcp_f32 (<=1 ulp); outputs bf16-compared (threshold 1.6)
__device__ __forceinline__ float rcpf(float x)
{
    float r; asm("v_rcp_f32 %0, %1" : "=v"(r) : "v"(x)); return r;
}

// 6th-root with downward margin. Margin 1e-4 >> ulp error of rcp/log/exp
// chains, so  metric > th  ==>  iou6 > th  ==>  inter > c*(uni+eps).
__device__ __forceinline__ float root6_down(float th)
{
    return exp2f(log2f(th) * (1.0f / 6.0f)) * 0.9999f;   // th=0 -> 0 (th>=0 always)
}

// iou^6 (no score) — argmax/fallback paths
__device__ __forceinline__ float iou6r(float4 g, float ga, float4 p)
{
    float pa = (p.z - p.x) * (p.w - p.y);
    float ltx = fmaxf(g.x, p.x), lty = fmaxf(g.y, p.y);
    float rbx = fminf(g.z, p.z), rby = fminf(g.w, p.w);
    float w = fmaxf(rbx - ltx, 0.0f), h = fmaxf(rby - lty, 0.0f);
    float inter = w * h;
    float uni = ga + pa - inter;
    float iou = inter * rcpf(uni + 1e-9f);
    float i2 = iou * iou;
    return i2 * i2 * i2;
}

// order-preserving float->uint map (total order; works for -FLT_MAX sentinel)
__device__ __forceinline__ unsigned f2ord(float f)
{
    unsigned b = __float_as_uint(f);
    return b ^ (unsigned)(((int)b >> 31) | 0x80000000);
}
__device__ __forceinline__ float ord2f(unsigned u)
{
    unsigned b = (u & 0x80000000u) ? (u ^ 0x80000000u) : ~u;
    return __uint_as_float(b);
}

// compare-swap: keep better (value desc, index asc) in (va, ia)
__device__ __forceinline__ void csw(float& va, int& ia, float& vb, int& ib)
{
    bool sw = (va < vb) || (va == vb && ia > ib);
    float tv = sw ? vb : va; int ti = sw ? ib : ia;
    vb = sw ? va : vb; ib = sw ? ia : ib;
    va = tv; ia = ti;
}

// wave-synchronous LDS fence
__device__ __forceinline__ void wsync()
{
    __builtin_amdgcn_sched_barrier(0);
    asm volatile("s_waitcnt lgkmcnt(0)" ::: "memory");
    __builtin_amdgcn_sched_barrier(0);
}

// Exact top-13 of {incumbents (lane r<13 holds rank r) ∪ cand[0..n)} where
// candidates are (inter, uni+eps, idx) triples. Computes the metric here with
// BIT-IDENTICAL op order (iou=in*rcp(ue); i6; m=sc*i6) and gathers scores
// (8/lane max). n <= 511. Returns the 13th-best metric (new threshold).
__device__ float flush_f(int lane, int n,
                         const float* c_in, const float* c_ue, const int* c_ix,
                         const float* __restrict__ srow,
                         float& inc_v, int& inc_i)
{
    wsync();                               // appended cand visible wave-wide
    float v[8]; int ix[8];
    #pragma unroll
    for (int k = 0; k < 8; ++k) {
        int j = lane + (k << 6);
        bool ok = j < n;
        float in = ok ? c_in[j] : 0.0f;
        float ue = ok ? c_ue[j] : 1.0f;
        int   ai = ok ? c_ix[j] : 0;
        float iou = in * rcpf(ue);
        float i2 = iou * iou;
        float i6 = i2 * i2 * i2;
        float sc = srow[ai];               // gather (flush-only)
        v[k]  = ok ? sc * i6 : -FLT_MAX;
        ix[k] = ok ? ai : 0x7fffffff;
    }
    csw(v[0],ix[0],v[1],ix[1]); csw(v[2],ix[2],v[3],ix[3]);
    csw(v[4],ix[4],v[5],ix[5]); csw(v[6],ix[6],v[7],ix[7]);
    csw(v[0],ix[0],v[2],ix[2]); csw(v[1],ix[1],v[3],ix[3]);
    csw(v[4],ix[4],v[6],ix[6]); csw(v[5],ix[5],v[7],ix[7]);
    csw(v[1],ix[1],v[2],ix[2]); csw(v[5],ix[5],v[6],ix[6]);
    csw(v[0],ix[0],v[4],ix[4]); csw(v[1],ix[1],v[5],ix[5]);
    csw(v[2],ix[2],v[6],ix[6]); csw(v[3],ix[3],v[7],ix[7]);
    csw(v[2],ix[2],v[4],ix[4]); csw(v[3],ix[3],v[5],ix[5]);
    csw(v[1],ix[1],v[2],ix[2]); csw(v[3],ix[3],v[4],ix[4]);
    csw(v[5],ix[5],v[6],ix[6]);
    bool c[8];
    #pragma unroll
    for (int j = 0; j < 8; ++j)
        c[j] = (v[j] > inc_v) || (v[j] == inc_v && ix[j] < inc_i);
    float h[9]; int hi[9];
    h[0] = c[0] ? v[0] : inc_v;  hi[0] = c[0] ? ix[0] : inc_i;
    #pragma unroll
    for (int j = 1; j < 8; ++j) {
        h[j]  = c[j] ? v[j]  : (c[j-1] ? inc_v : v[j-1]);
        hi[j] = c[j] ? ix[j] : (c[j-1] ? inc_i : ix[j-1]);
    }
    h[8] = c[7] ? inc_v : v[7];  hi[8] = c[7] ? inc_i : ix[7];

    float th = -FLT_MAX;
    #pragma unroll
    for (int r = 0; r < KK; ++r) {
        ull myp = ((ull)f2ord(h[0]) << 32) | (unsigned)(~hi[0]);
        ull p = myp;
        #pragma unroll
        for (int o = 32; o >= 1; o >>= 1) {
            ull q = __shfl_xor(p, o);
            p = p > q ? p : q;
        }
        float wv = ord2f((unsigned)(p >> 32));
        int   wi = (int)~((unsigned)p);
        if (lane == r) { inc_v = wv; inc_i = wi; }
        bool pop = (myp == p);
        #pragma unroll
        for (int j = 0; j < 8; ++j) {
            h[j]  = pop ? h[j+1]  : h[j];
            hi[j] = pop ? hi[j+1] : hi[j];
        }
        h[8]  = pop ? -FLT_MAX   : h[8];
        hi[8] = pop ? 0x7fffffff : hi[8];
        th = wv;
    }
    return th;
}

// Insert into register-resident sorted-13 (fallback kernels only).
__device__ __forceinline__ void insert13(float* v, int* ix, float m, int a)
{
    bool worse = (m < v[KK - 1]) || (m == v[KK - 1] && a > ix[KK - 1]);
    if (worse) return;
    int p = 0;
    #pragma unroll
    for (int j = 0; j < KK; ++j)
        p += ((v[j] > m) || (v[j] == m && ix[j] < a)) ? 1 : 0;
    #pragma unroll
    for (int j = KK - 1; j >= 1; --j) {
        bool sh = (j > p);
        v[j]  = sh ? v[j - 1]  : v[j];
        ix[j] = sh ? ix[j - 1] : ix[j];
    }
    #pragma unroll
    for (int j = 0; j < KK; ++j) if (j == p) { v[j] = m; ix[j] = a; }
}

// ---------------- pd_scores [AN][NC] -> scT [NC][AN] ----------------
__global__ __launch_bounds__(256) void transpose_scores(
    const float* __restrict__ ps, float* __restrict__ scT)
{
    __shared__ float tile[64][NC + 1];
    int a0 = blockIdx.x * 64;
    int tid = threadIdx.x;
    for (int i = tid; i < 64 * NC / 4; i += 256) {
        int fi = i * 4;
        int a = fi / NC, c = fi % NC;
        if (a0 + a < AN) {
            float4 v = *reinterpret_cast<const float4*>(ps + (size_t)(a0 + a) * NC + c);
            tile[a][c] = v.x; tile[a][c + 1] = v.y; tile[a][c + 2] = v.z; tile[a][c + 3] = v.w;
        }
    }
    __syncthreads();
    int j = tid & 63, cg = tid >> 6;
    int a = a0 + j;
    if (a < AN) {
        for (int c = cg; c < NC; c += 4)
            scT[(size_t)c * AN + a] = tile[j][c];
    }
}

// ---------------- argmax pass A1 (predicated) ----------------
__global__ __launch_bounds__(256) void argmax_part(
    const float* __restrict__ pd_bboxes,
    const int*   __restrict__ gt_labels,
    const float* __restrict__ gt_bboxes,
    const float* __restrict__ scT,
    ull* __restrict__ part)
{
    __shared__ float4 gb[GPS];
    __shared__ float  ga[GPS];
    __shared__ int    glb[GPS];
    int slice = blockIdx.x & (GSLICE - 1);
    int ab = (blockIdx.x >> 3) * 512;
    int tid = threadIdx.x;
    int g0 = slice * GPS;
    if (tid < GPS) {
        float4 bb = ((const float4*)gt_bboxes)[g0 + tid];
        gb[tid] = bb;
        ga[tid] = (bb.z - bb.x) * (bb.w - bb.y);
        glb[tid] = gt_labels[g0 + tid];
    }
    __syncthreads();
    int aa = ab + tid, ab2 = ab + 256 + tid;
    bool okA = aa < AN, okB = ab2 < AN;
    int ca = okA ? aa : AN - 1, cb = okB ? ab2 : AN - 1;
    float4 pba = ((const float4*)pd_bboxes)[ca];
    float4 pbb = ((const float4*)pd_bboxes)[cb];
    float bestA = -1.0f, bestB = -1.0f;
    int bgA = 0, bgB = 0;
    for (int i = 0; i < GPS; ++i) {
        float4 gx = gb[i];
        float gax = ga[i];
        int lab = glb[i];
        const float* srow = scT + (size_t)lab * AN;
        float i6a = iou6r(gx, gax, pba);
        float i6b = iou6r(gx, gax, pbb);
        float sa = (i6a > bestA) ? srow[ca] : 0.0f;   // predicated gather
        float sb = (i6b > bestB) ? srow[cb] : 0.0f;
        float ma = sa * i6a;
        float mb = sb * i6b;
        if (ma > bestA) { bestA = ma; bgA = i; }      // strict > => first-occurrence
        if (mb > bestB) { bestB = mb; bgB = i; }
    }
    if (okA)
        part[(size_t)slice * AN + aa] =
            ((ull)__float_as_uint(bestA) << 32) | (ull)(0xFFFFFFFFu - (unsigned)(g0 + bgA));
    if (okB)
        part[(size_t)slice * AN + ab2] =
            ((ull)__float_as_uint(bestB) << 32) | (ull)(0xFFFFFFFFu - (unsigned)(g0 + bgB));
}

// ---------------- argmax pass A2 ----------------
__global__ __launch_bounds__(256) void argmax_combine(
    const ull* __restrict__ part,
    const int* __restrict__ gt_labels,
    const float* __restrict__ gt_bboxes,
    float* __restrict__ out)
{
    int a = blockIdx.x * 256 + threadIdx.x;
    if (a >= AN) return;
    ull p = part[a];
    #pragma unroll
    for (int s = 1; s < GSLICE; ++s) {
        ull q = part[(size_t)s * AN + a];
        p = p > q ? p : q;
    }
    unsigned g = 0xFFFFFFFFu - (unsigned)(p & 0xFFFFFFFFull);
    float best = __uint_as_float((unsigned)(p >> 32));
    out[a] = (best <= 0.0f) ? (float)NC : (float)gt_labels[g];
    ((float4*)(out + AN))[a] = ((const float4*)gt_bboxes)[g];
    out[(size_t)5 * AN + a] = best;
}

// ---------------- topk pass 1 ----------------
// 4 waves/block at lb(256,4) — VGPR cap 128, no spilling (NEVER lb(,8):
// its 32-VGPR cap caused ~500MB scratch traffic in rounds 9/11).
// Division-free hot loop: inter > cth*(uni+eps) superset filter, THIN append
// of the raw (inter, uni+eps, idx) triple. Flush computes the exact metric
// (bit-identical op order) + gathers scores + exact selection.
__device__ __forceinline__ void loadB(int tb, int lane,
    const float4* __restrict__ pd4,
    float4& B0, float4& B1, float4& B2, float4& B3)
{
    int a0 = tb + lane;
    B0 = pd4[min(a0,       AN - 1)];
    B1 = pd4[min(a0 + 64,  AN - 1)];
    B2 = pd4[min(a0 + 128, AN - 1)];
    B3 = pd4[min(a0 + 192, AN - 1)];
}

__device__ __forceinline__ void procB(
    int tb, int aend, int lane, uint64_t lt,
    float4 B0, float4 B1, float4 B2, float4 B3,
    const float* __restrict__ srow,
    float4 b, float gax, float& th, float& cth, int& cnt,
    float* c_in, float* c_ue, int* c_ix,
    float& inc_v, int& inc_i)
{
    int a0 = tb + lane, a1 = a0 + 64, a2 = a0 + 128, a3 = a0 + 192;
    float lx0 = fmaxf(b.x, B0.x), ly0 = fmaxf(b.y, B0.y);
    float rx0 = fminf(b.z, B0.z), ry0 = fminf(b.w, B0.w);
    float w0 = fmaxf(rx0 - lx0, 0.0f), h0f = fmaxf(ry0 - ly0, 0.0f);
    float in0 = w0 * h0f;
    float ue0 = gax + (B0.z - B0.x) * (B0.w - B0.y) - in0 + 1e-9f;
    float lx1 = fmaxf(b.x, B1.x), ly1 = fmaxf(b.y, B1.y);
    float rx1 = fminf(b.z, B1.z), ry1 = fminf(b.w, B1.w);
    float w1 = fmaxf(rx1 - lx1, 0.0f), h1f = fmaxf(ry1 - ly1, 0.0f);
    float in1 = w1 * h1f;
    float ue1 = gax + (B1.z - B1.x) * (B1.w - B1.y) - in1 + 1e-9f;
    float lx2 = fmaxf(b.x, B2.x), ly2 = fmaxf(b.y, B2.y);
    float rx2 = fminf(b.z, B2.z), ry2 = fminf(b.w, B2.w);
    float w2 = fmaxf(rx2 - lx2, 0.0f), h2f = fmaxf(ry2 - ly2, 0.0f);
    float in2 = w2 * h2f;
    float ue2 = gax + (B2.z - B2.x) * (B2.w - B2.y) - in2 + 1e-9f;
    float lx3 = fmaxf(b.x, B3.x), ly3 = fmaxf(b.y, B3.y);
    float rx3 = fminf(b.z, B3.z), ry3 = fminf(b.w, B3.w);
    float w3 = fmaxf(rx3 - lx3, 0.0f), h3f = fmaxf(ry3 - ly3, 0.0f);
    float in3 = w3 * h3f;
    float ue3 = gax + (B3.z - B3.x) * (B3.w - B3.y) - in3 + 1e-9f;
    // superset filter: m > th ==> iou6 > th ==> inter > cth*(uni+eps)
    bool h0 = (in0 > cth * ue0) && (a0 < aend);
    bool h1 = (in1 > cth * ue1) && (a1 < aend);
    bool h2 = (in2 > cth * ue2) && (a2 < aend);
    bool h3 = (in3 > cth * ue3) && (a3 < aend);
    if (__any(h0 | h1 | h2 | h3)) {
        uint64_t B;
        B = __ballot(h0);
        if (h0) { int p = cnt + __popcll(B & lt); c_in[p] = in0; c_ue[p] = ue0; c_ix[p] = a0; }
        cnt += __popcll(B);
        B = __ballot(h1);
        if (h1) { int p = cnt + __popcll(B & lt); c_in[p] = in1; c_ue[p] = ue1; c_ix[p] = a1; }
        cnt += __popcll(B);
        B = __ballot(h2);
        if (h2) { int p = cnt + __popcll(B & lt); c_in[p] = in2; c_ue[p] = ue2; c_ix[p] = a2; }
        cnt += __popcll(B);
        B = __ballot(h3);
        if (h3) { int p = cnt + __popcll(B & lt); c_in[p] = in3; c_ue[p] = ue3; c_ix[p] = a3; }
        cnt += __popcll(B);
        if (cnt >= 256) {                 // cap: 255 + 256 = 511 < 512
            th = flush_f(lane, cnt, c_in, c_ue, c_ix, srow, inc_v, inc_i);
            cth = root6_down(th);         // th >= 0 after any 256-flush
            cnt = 0;
        }
    }
}

__global__ __launch_bounds__(256, 4) void topk_pass1(
    const float* __restrict__ pd_bboxes,
    const int*   __restrict__ gt_labels,
    const float* __restrict__ gt_bboxes,
    const float* __restrict__ scT,
    float* __restrict__ out_v, int* __restrict__ out_i)
{
    __shared__ float cinA[4][512];
    __shared__ float cueA[4][512];
    __shared__ int   cixA[4][512];
    int w = threadIdx.x >> 6, lane = threadIdx.x & 63;
    float* c_in = cinA[w]; float* c_ue = cueA[w]; int* c_ix = cixA[w];
    uint64_t lt = (1ull << lane) - 1ull;
    int gid = blockIdx.x * 4 + w;
    int g = gid & (GN - 1), c = gid >> 9;

    float4 b = ((const float4*)gt_bboxes)[g];
    float gax = (b.z - b.x) * (b.w - b.y);
    int lab = gt_labels[g];
    const float* srow = scT + (size_t)lab * AN;
    const float4* pd4 = (const float4*)pd_bboxes;

    int base = c * CH_LEN;
    int len = min(CH_LEN, AN - base);
    int aend = base + len;
    int NT = (len + 255) >> 8;

    float th = -FLT_MAX, cth = -FLT_MAX;   // first tile floods -> first flush
    int cnt = 0;
    float inc_v = -FLT_MAX; int inc_i = 0x7fffffff;   // lane r<13: rank r

    float4 X0, X1, X2, X3, Y0, Y1, Y2, Y3;
    loadB(base, lane, pd4, X0, X1, X2, X3);
    int i = 0, tb = base;
    while (true) {
        if (i + 1 < NT) loadB(tb + 256, lane, pd4, Y0, Y1, Y2, Y3);
        procB(tb, aend, lane, lt, X0, X1, X2, X3, srow,
              b, gax, th, cth, cnt, c_in, c_ue, c_ix, inc_v, inc_i);
        ++i; tb += 256;
        if (i >= NT) break;
        if (i + 1 < NT) loadB(tb + 256, lane, pd4, X0, X1, X2, X3);
        procB(tb, aend, lane, lt, Y0, Y1, Y2, Y3, srow,
              b, gax, th, cth, cnt, c_in, c_ue, c_ix, inc_v, inc_i);
        ++i; tb += 256;
        if (i >= NT) break;
    }

    if (cnt > 0)
        flush_f(lane, cnt, c_in, c_ue, c_ix, srow, inc_v, inc_i);

    if (lane < DUMP) {
        size_t o = ((size_t)g * CHUNKS + c) * DUMP + lane;
        out_v[o] = (lane < KK) ? inc_v : -FLT_MAX;
        out_i[o] = (lane < KK) ? inc_i : 0x7fffffff;
    }
}

// ---------------- topk pass 2: zero row + merge 8x16 dumps + scatter ----------------
__global__ __launch_bounds__(256) void topk_finalize(
    const float* __restrict__ in_v, const int* __restrict__ in_i,
    float* __restrict__ mask)
{
    int g = blockIdx.x, tid = threadIdx.x;
    float4* row4 = (float4*)(mask + (size_t)g * AN);
    float4 z = make_float4(0.f, 0.f, 0.f, 0.f);
    for (int j = tid; j < AN / 4; j += 256) row4[j] = z;
    __syncthreads();
    if (tid >= 64) return;
    int lane = tid;
    size_t rb = (size_t)g * (CHUNKS * DUMP);     // 128 entries
    float v0 = in_v[rb + lane], v1 = in_v[rb + 64 + lane];
    int   i0 = in_i[rb + lane], i1 = in_i[rb + 64 + lane];
    csw(v0, i0, v1, i1);
    #pragma unroll
    for (int r = 0; r < KK; ++r) {
        ull myp = ((ull)f2ord(v0) << 32) | (unsigned)(~i0);
        ull p = myp;
        #pragma unroll
        for (int o = 32; o >= 1; o >>= 1) {
            ull q = __shfl_xor(p, o);
            p = p > q ? p : q;
        }
        int wi = (int)~((unsigned)p);
        if (lane == r) mask[(size_t)g * AN + wi] = 1.0f;
        bool pop = (myp == p);
        v0 = pop ? v1 : v0;          i0 = pop ? i1 : i0;
        v1 = pop ? -FLT_MAX : v1;    i1 = pop ? 0x7fffffff : i1;
    }
}

// ---------------- fallbacks (small workspace) ----------------
__global__ __launch_bounds__(256) void argmax_kernel(
    const float* __restrict__ pd_scores,
    const float* __restrict__ pd_bboxes,
    const int*   __restrict__ gt_labels,
    const float* __restrict__ gt_bboxes,
    const float* __restrict__ scT, int use_t,
    float* __restrict__ out)
{
    __shared__ float4 gb[GN];
    __shared__ float  ga[GN];
    __shared__ int    gl[GN];
    int tid = threadIdx.x;
    for (int g = tid; g < GN; g += 256) {
        float4 b = reinterpret_cast<const float4*>(gt_bboxes)[g];
        gb[g] = b;
        ga[g] = (b.z - b.x) * (b.w - b.y);
        gl[g] = gt_labels[g];
    }
    __syncthreads();
    int a = blockIdx.x * 256 + tid;
    if (a >= AN) return;
    float4 pb = reinterpret_cast<const float4*>(pd_bboxes)[a];
    float best = -1.0f; int bg = 0;
    for (int g = 0; g < GN; ++g) {
        int lab = gl[g];
        float sc = use_t ? scT[(size_t)lab * AN + a] : pd_scores[(size_t)a * NC + lab];
        float m = sc * iou6r(gb[g], ga[g], pb);
        if (m > best) { best = m; bg = g; }
    }
    out[a] = (best <= 0.0f) ? (float)NC : (float)gl[bg];
    reinterpret_cast<float4*>(out + AN)[a] = gb[bg];
    out[5 * AN + a] = best;
}

__global__ __launch_bounds__(256) void topk_kernel_fallback(
    const float* __restrict__ pd_scores,
    const float* __restrict__ pd_bboxes,
    const int*   __restrict__ gt_labels,
    const float* __restrict__ gt_bboxes,
    const float* __restrict__ scT, int use_t,
    float* __restrict__ mask)
{
    __shared__ float sv[256 * KK];
    __shared__ int   si[256 * KK];
    int g = blockIdx.x, tid = threadIdx.x;
    float4 b = reinterpret_cast<const float4*>(gt_bboxes)[g];
    float gax = (b.z - b.x) * (b.w - b.y);
    int lab = gt_labels[g];
    float v[KK]; int idx[KK];
    #pragma unroll
    for (int j = 0; j < KK; ++j) { v[j] = -FLT_MAX; idx[j] = 0x7fffffff; }
    for (int a = tid; a < AN; a += 256) {
        float4 pb = reinterpret_cast<const float4*>(pd_bboxes)[a];
        float sc = use_t ? scT[(size_t)lab * AN + a] : pd_scores[(size_t)a * NC + lab];
        float m = sc * iou6r(b, gax, pb);
        insert13(v, idx, m, a);
    }
    #pragma unroll
    for (int j = 0; j < KK; ++j) { sv[tid * KK + j] = v[j]; si[tid * KK + j] = idx[j]; }
    for (int off = 128; off >= 1; off >>= 1) {
        __syncthreads();
        if (tid < off) {
            int i = 0, jj = 0;
            float ov[KK]; int oi[KK];
            #pragma unroll
            for (int t = 0; t < KK; ++t) {
                float va = sv[tid * KK + i];          int ia = si[tid * KK + i];
                float vb = sv[(tid + off) * KK + jj]; int ib = si[(tid + off) * KK + jj];
                bool ta = (va > vb) || (va == vb && ia < ib);
                ov[t] = ta ? va : vb; oi[t] = ta ? ia : ib;
                i += ta ? 1 : 0; jj += ta ? 0 : 1;
            }
            #pragma unroll
            for (int t = 0; t < KK; ++t) { sv[tid * KK + t] = ov[t]; si[tid * KK + t] = oi[t]; }
        }
    }
    __syncthreads();
    if (tid < KK) mask[(size_t)g * AN + si[tid]] = 1.0f;
}

extern "C" void kernel_launch(void* const* d_in, const int* in_sizes, int n_in,
                              void* d_out, int out_size, void* d_ws, size_t ws_size,
                              hipStream_t stream)
{
    const float* pd_scores = (const float*)d_in[0];
    const float* pd_bboxes = (const float*)d_in[1];
    const int*   gt_labels = (const int*)d_in[2];
    const float* gt_bboxes = (const float*)d_in[3];
    float* out  = (float*)d_out;
    float* mask = out + (size_t)6 * AN;

    const size_t scT_b  = (size_t)NC * AN * sizeof(float);           // 32.0 MB
    const size_t auxn   = (size_t)GN * CHUNKS * DUMP;                // 65536
    const size_t aux_b  = auxn * 8;                                  // 0.5 MB
    const size_t part_b = (size_t)GSLICE * AN * sizeof(ull);         // 6.4 MB

    float* scT   = (float*)d_ws;
    float* aux_v = (float*)((char*)d_ws + scT_b);
    int*   aux_i = (int*)(aux_v + auxn);
    ull*   part  = (ull*)((char*)d_ws + scT_b + aux_b);

    if (ws_size >= scT_b + aux_b + part_b) {
        transpose_scores<<<(AN + 63) / 64, 256, 0, stream>>>(pd_scores, scT);
        topk_pass1<<<GN * CHUNKS / 4, 256, 0, stream>>>(
            pd_bboxes, gt_labels, gt_bboxes, scT, aux_v, aux_i);
        topk_finalize<<<GN, 256, 0, stream>>>(aux_v, aux_i, mask);
        argmax_part<<<((AN + 511) / 512) * GSLICE, 256, 0, stream>>>(
            pd_bboxes, gt_labels, gt_bboxes, scT, part);
        argmax_combine<<<(AN + 255) / 256, 256, 0, stream>>>(
            part, gt_labels, gt_bboxes, out);
    } else if (ws_size >= scT_b + aux_b) {
        transpose_scores<<<(AN + 63) / 64, 256, 0, stream>>>(pd_scores, scT);
        topk_pass1<<<GN * CHUNKS / 4, 256, 0, stream>>>(
            pd_bboxes, gt_labels, gt_bboxes, scT, aux_v, aux_i);
        topk_finalize<<<GN, 256, 0, stream>>>(aux_v, aux_i, mask);
        argmax_kernel<<<(AN + 255) / 256, 256, 0, stream>>>(
            pd_scores, pd_bboxes, gt_labels, gt_bboxes, scT, 1, out);
    } else if (ws_size >= scT_b) {
        hipMemsetAsync(mask, 0, (size_t)GN * AN * sizeof(float), stream);
        transpose_scores<<<(AN + 63) / 64, 256, 0, stream>>>(pd_scores, scT);
        argmax_kernel<<<(AN + 255) / 256, 256, 0, stream>>>(
            pd_scores, pd_bboxes, gt_labels, gt_bboxes, scT, 1, out);
        topk_kernel_fallback<<<GN, 256, 0, stream>>>(
            pd_scores, pd_bboxes, gt_labels, gt_bboxes, scT, 1, mask);
    } else {
        hipMemsetAsync(mask, 0, (size_t)GN * AN * sizeof(float), stream);
        argmax_kernel<<<(AN + 255) / 256, 256, 0, stream>>>(
            pd_scores, pd_bboxes, gt_labels, gt_bboxes, scT, 0, out);
        topk_kernel_fallback<<<GN, 256, 0, stream>>>(
            pd_scores, pd_bboxes, gt_labels, gt_bboxes, scT, 0, mask);
    }
}